// Round 14
// baseline (181.373 us; speedup 1.0000x reference)
//
#include <hip/hip_runtime.h>
#include <cstddef>

typedef _Float16 h8 __attribute__((ext_vector_type(8)));
typedef float f4 __attribute__((ext_vector_type(4)));
typedef unsigned int uint32;

// ---------------- prep kernel: synthesize merged 17x17 kernels ----------------
struct BranchP {
  int ksz, scale, CIN, HID, COUT, S, nd;
  int dils[3];
  const float *dw_w, *dw_b, *w1, *b1, *w2, *b2, *dilw;
};

__device__ void run_branch(int tid, const BranchP P,
                           const float* w0, float* merged,
                           float* bufA, float* bufB) {
  const int S = P.S, ksz = P.ksz, CIN = P.CIN, HID = P.HID, COUT = P.COUT;
  const int SS = S * S;
  // 1) pad (bottom/right) + pixel_unshuffle (scale==1 -> copy)
  for (int i = tid; i < CIN * SS; i += 256) {
    const int cc = i / SS, rem = i % SS, hh = rem / S, ww = rem % S;
    const int s2 = P.scale * P.scale;
    const int c = cc / s2, r2 = cc % s2, si = r2 / P.scale, sj = r2 % P.scale;
    const int sh = hh * P.scale + si, sw = ww * P.scale + sj;
    bufA[i] = (sh < 17 && sw < 17) ? w0[c * 289 + sh * 17 + sw] : 0.f;
  }
  __syncthreads();
  // 2) depthwise 3x3, pad 1
  for (int i = tid; i < CIN * SS; i += 256) {
    const int ch = i / SS, rem = i % SS, y = rem / S, x = rem % S;
    float acc = P.dw_b[ch];
    for (int u = 0; u < 3; ++u)
      for (int v = 0; v < 3; ++v) {
        const int yy = y + u - 1, xx = x + v - 1;
        if (yy >= 0 && yy < S && xx >= 0 && xx < S)
          acc += bufA[ch * SS + yy * S + xx] * P.dw_w[ch * 9 + u * 3 + v];
      }
    bufB[i] = acc;
  }
  __syncthreads();
  // 3) 1x1 + bias + relu  (bufB -> bufA)
  for (int i = tid; i < HID * SS; i += 256) {
    const int ho = i / SS, rem = i % SS;
    float acc = P.b1[ho];
    for (int ci = 0; ci < CIN; ++ci) acc += bufB[ci * SS + rem] * P.w1[ho * CIN + ci];
    bufA[i] = fmaxf(acc, 0.f);
  }
  __syncthreads();
  // 4) 1x1 + bias  (bufA -> bufB)
  for (int i = tid; i < COUT * SS; i += 256) {
    const int po = i / SS, rem = i % SS;
    float acc = P.b2[po];
    for (int ci = 0; ci < HID; ++ci) acc += bufA[ci * SS + rem] * P.w2[po * HID + ci];
    bufB[i] = acc;
  }
  __syncthreads();
  // 5) bilinear S -> ksz  (bufB -> bufA)
  for (int i = tid; i < COUT * ksz * ksz; i += 256) {
    const int c = i / (ksz * ksz), rem = i % (ksz * ksz), oy = rem / ksz, ox = rem % ksz;
    const float ratio = (float)S / (float)ksz;
    float sy = fminf(fmaxf((oy + 0.5f) * ratio - 0.5f, 0.f), (float)(S - 1));
    float sx = fminf(fmaxf((ox + 0.5f) * ratio - 0.5f, 0.f), (float)(S - 1));
    const int y0 = (int)sy; const int y1 = min(y0 + 1, S - 1); const float ty = sy - (float)y0;
    const int x0 = (int)sx; const int x1 = min(x0 + 1, S - 1); const float tx = sx - (float)x0;
    const float* img = bufB + c * SS;
    const float top = img[y0 * S + x0] * (1.f - tx) + img[y0 * S + x1] * tx;
    const float bot = img[y1 * S + x0] * (1.f - tx) + img[y1 * S + x1] * tx;
    bufA[i] = top * (1.f - ty) + bot * ty;
  }
  __syncthreads();
  // 6) per-dil channel mix + zero-interleave + accumulate into merged
  for (int di = 0; di < P.nd; ++di) {
    const int d = P.dils[di];
    const int e = d * (ksz - 1) + 1, pp = 8 - e / 2;
    for (int i = tid; i < 3 * ksz * ksz; i += 256) {
      const int p = i / (ksz * ksz), rem = i % (ksz * ksz), ih = rem / ksz, iw = rem % ksz;
      float acc = 0.f;
      for (int c2 = 0; c2 < COUT; ++c2)
        acc += bufA[c2 * ksz * ksz + rem] * P.dilw[(di * 3 + p) * COUT + c2];
      merged[p * 289 + (pp + d * ih) * 17 + (pp + d * iw)] += acc;
    }
  }
  __syncthreads();
}

// A-matrix geometry: K = 17 dx-cols x 24 rows = 408, padded to 416 (13 x K32).
//   k = dxi*24 + r ; dxi = dx+8 in [0,16] ; r = local X row (rel. to ygroup base).
//   G1 (M=16): m = y_off*2 + pp, pp in {0,1};  G2: m = y_off (p=2), m>=8 zero.
//   A[m][k] = merged[pp][dy+8][dxi], dy = r - 8 - y_off (zero outside [-8,8]).
#define KPAD 416
#define ACH (2 * 16 * KPAD)   // f16 elements per channel (both GEMMs)

__global__ __launch_bounds__(256) void prep_kernel(
    const float* __restrict__ A1, const float* __restrict__ B1,
    const float* __restrict__ A2, const float* __restrict__ B2,
    const float* __restrict__ A3, const float* __restrict__ B3,
    const float* __restrict__ dw_w3, const float* __restrict__ dw_b3,
    const float* __restrict__ w1_3, const float* __restrict__ b1_3,
    const float* __restrict__ w2_3, const float* __restrict__ b2_3,
    const float* __restrict__ dilw3,
    const float* __restrict__ dw_w5, const float* __restrict__ dw_b5,
    const float* __restrict__ w1_5, const float* __restrict__ b1_5,
    const float* __restrict__ w2_5, const float* __restrict__ b2_5,
    const float* __restrict__ dilw5,
    const float* __restrict__ dw_w9, const float* __restrict__ dw_b9,
    const float* __restrict__ w1_9, const float* __restrict__ b1_9,
    const float* __restrict__ w2_9, const float* __restrict__ b2_9,
    const float* __restrict__ dilw9,
    _Float16* __restrict__ wA) {
  const int o = blockIdx.x;
  const int tid = threadIdx.x;
  __shared__ float w0[3 * 289];
  __shared__ float merged[3 * 289];
  __shared__ float bufA[3888];
  __shared__ float bufB[3888];

  // weight0[o,c] = A_c[o] (17x4) @ B_c[o] (4x17)
  for (int i = tid; i < 3 * 289; i += 256) {
    const int c = i / 289, rem = i % 289, k = rem / 17, l = rem % 17;
    const float* A = (c == 0 ? A1 : (c == 1 ? A2 : A3)) + o * 68;
    const float* B = (c == 0 ? B1 : (c == 1 ? B2 : B3)) + o * 68;
    float s = 0.f;
    for (int r = 0; r < 4; ++r) s += A[k * 4 + r] * B[r * 17 + l];
    w0[i] = s;
    merged[i] = 0.f;
  }
  __syncthreads();

  {
    BranchP P{3, 4, 48, 64, 12, 5, 3, {4, 5, 7}, dw_w3, dw_b3, w1_3, b1_3, w2_3, b2_3, dilw3};
    run_branch(tid, P, w0, merged, bufA, bufB);
  }
  {
    BranchP P{5, 2, 12, 48, 6, 9, 1, {1, 0, 0}, dw_w5, dw_b5, w1_5, b1_5, w2_5, b2_5, dilw5};
    run_branch(tid, P, w0, merged, bufA, bufB);
  }
  {
    BranchP P{9, 1, 3, 12, 3, 17, 1, {2, 0, 0}, dw_w9, dw_b9, w1_9, b1_9, w2_9, b2_9, dilw9};
    run_branch(tid, P, w0, merged, bufA, bufB);
  }

  // pack A-matrices (f16, RTE) for both GEMMs
  for (int i = tid; i < ACH; i += 256) {
    const int g = i / (16 * KPAD);
    const int m = (i / KPAD) % 16;
    const int k = i % KPAD;
    const int dxi = k / 24, r = k % 24;
    int pp, yo;
    if (g == 0) { pp = m & 1; yo = m >> 1; } else { pp = 2; yo = m; }
    const int dy = r - 8 - yo;
    float val = 0.f;
    if (!(g == 1 && m >= 8) && dy >= -8 && dy <= 8 && dxi <= 16)
      val = merged[pp * 289 + (dy + 8) * 17 + dxi];
    wA[(size_t)o * ACH + i] = (_Float16)val;
  }
}

// ---------------- main conv kernel (MFMA, persistent y-strip, dbuf) ----------------
// 512 blocks (2/CU resident), each owns one (n,ch) strip = 8 items x 32 rows.
// Cross-item LDS double-buffer (R13), plus two R14 fixes:
//  (1) stage prefetch DISTANCE 2: batch q loads at pair q, writes at pair q+2
//      (~1100 cyc > 900-cyc HBM latency; was 1 pair = 550 cyc -> ~350 cyc stall
//      per batch). Two batches in flight in pvA/pvB (compile-time selected).
//  (2) raw s_barrier + lgkmcnt(0)-only per item (no vmcnt(0) store drain --
//      item outputs are disjoint; only LDS ordering is needed). sched_barrier
//      fences pin LDS ops on each side of the inline-asm waitcnt.
__global__ __launch_bounds__(256, 2) void conv_mfma_kernel(
    const float* __restrict__ xin, const _Float16* __restrict__ wA,
    float* __restrict__ out) {
  const int blk = ((blockIdx.x & 7) << 6) + (blockIdx.x >> 3);
  const int n  = blk >> 6;
  const int ch = blk & 63;
  const int tid = threadIdx.x;

#define PITCH 56
  __shared__ __align__(16) _Float16 Xt[2][280 * PITCH];  // 2 x 31,360 B

  const float* xim = xin + ((size_t)(n * 64 + ch)) * 65536;

  const int lane = tid & 63;
  const int wv = tid >> 6;
  const int row = lane & 15;   // A-row / B-col / C-col lane index
  const int kg = lane >> 4;    // k-slice group (8 k's each)

  // ---- A fragments: loaded once per block, reused for all 8 items ----
  h8 a1[13], a2[13];
  {
    const _Float16* Ab = wA + (size_t)ch * ACH + row * KPAD;
    #pragma unroll
    for (int t = 0; t < 13; ++t) {
      const int k0 = t * 32 + kg * 8;
      a1[t] = __builtin_bit_cast(h8, *(const uint4*)(Ab + k0));
      a2[t] = __builtin_bit_cast(h8, *(const uint4*)(Ab + 16 * KPAD + k0));
    }
  }

  // ---- B-fragment LDS offsets (item-independent) ----
  int boff[13];
  #pragma unroll
  for (int t = 0; t < 13; ++t) {
    const int k0 = t * 32 + kg * 8;
    const int dxi = k0 / 24, r0 = k0 - dxi * 24;   // 8 consecutive k in one dxi
    boff[t] = (row + dxi) * PITCH + r0;
  }

  // ---- prologue: stage item 0 (rows -8..39) into Xt[0] ----
  for (int i = tid; i < 6 * 280; i += 256) {
    const int rb = i / 280, c = i % 280;
    const int gx = c - 8;
    const bool cok = (gx >= 0 && gx < 256);
    float v[8];
    #pragma unroll
    for (int rr = 0; rr < 8; ++rr) {
      const int gy = -8 + rb * 8 + rr;
      v[rr] = (cok && gy >= 0 && gy < 256) ? xim[gy * 256 + gx] : 0.f;
    }
    uint4 u;
    u.x = __builtin_bit_cast(uint32, __builtin_amdgcn_cvt_pkrtz(v[0], v[1]));
    u.y = __builtin_bit_cast(uint32, __builtin_amdgcn_cvt_pkrtz(v[2], v[3]));
    u.z = __builtin_bit_cast(uint32, __builtin_amdgcn_cvt_pkrtz(v[4], v[5]));
    u.w = __builtin_bit_cast(uint32, __builtin_amdgcn_cvt_pkrtz(v[6], v[7]));
    *(uint4*)&Xt[0][c * PITCH + rb * 8] = u;
  }
  __syncthreads();

  float pvA[8], pvB[8];   // two stage batches in flight (even / odd)

#define LOAD_BATCH(q) do {                                                     \
    const int il = tid + 256 * (q);                                            \
    if (il < 1680) {                                                           \
      float* pv_ = ((q) & 1) ? pvB : pvA;                                      \
      const int rbl = il / 280, ccl = il % 280;                                \
      const int gx = ccl - 8;                                                  \
      const bool cok = (gx >= 0 && gx < 256);                                  \
      _Pragma("unroll")                                                        \
      for (int rr = 0; rr < 8; ++rr) {                                         \
        const int gy = ygn - 8 + rbl * 8 + rr;                                 \
        pv_[rr] = (cok && gy >= 0 && gy < 256) ? xim[gy * 256 + gx] : 0.f;     \
      }                                                                        \
    }                                                                          \
  } while (0)

#define WRITE_BATCH(q) do {                                                    \
    const int ip = tid + 256 * (q);                                            \
    if (ip < 1680) {                                                           \
      const float* pv_ = ((q) & 1) ? pvB : pvA;                                \
      const int rbp = ip / 280, ccp = ip % 280;                                \
      uint4 u;                                                                 \
      u.x = __builtin_bit_cast(uint32, __builtin_amdgcn_cvt_pkrtz(pv_[0], pv_[1])); \
      u.y = __builtin_bit_cast(uint32, __builtin_amdgcn_cvt_pkrtz(pv_[2], pv_[3])); \
      u.z = __builtin_bit_cast(uint32, __builtin_amdgcn_cvt_pkrtz(pv_[4], pv_[5])); \
      u.w = __builtin_bit_cast(uint32, __builtin_amdgcn_cvt_pkrtz(pv_[6], pv_[7])); \
      *(uint4*)&nxtp[ccp * PITCH + rbp * 8] = u;                               \
    }                                                                          \
  } while (0)

#define MSTEP(t) do {                                                          \
    const h8 vba = __builtin_bit_cast(h8, *(const uint4*)&curp[ba_ + boff[t]]);\
    const h8 vbb = __builtin_bit_cast(h8, *(const uint4*)&curp[bb_ + boff[t]]);\
    c1a = __builtin_amdgcn_mfma_f32_16x16x32_f16(a1[t], vba, c1a, 0, 0, 0);    \
    c1b = __builtin_amdgcn_mfma_f32_16x16x32_f16(a1[t], vbb, c1b, 0, 0, 0);    \
    c2a = __builtin_amdgcn_mfma_f32_16x16x32_f16(a2[t], vba, c2a, 0, 0, 0);    \
    c2b = __builtin_amdgcn_mfma_f32_16x16x32_f16(a2[t], vbb, c2b, 0, 0, 0);    \
  } while (0)

#define PAIR_BLOCK(pr) do {                                                    \
    /* write stage batch pr-2 (loaded two pairs ago; ~1100 cyc in flight) */   \
    if (pf && (pr) >= 2) WRITE_BATCH((pr) - 2);                                \
    /* issue stage batch pr loads */                                           \
    if (pf && (pr) <= 6) LOAD_BATCH(pr);                                       \
    /* compute pair */                                                         \
    {                                                                          \
      const int g_ = (pr) >> 1, cp_ = (pr) & 1;                                \
      const int j0a_ = (wv * 4 + cp_ * 2) * 16;                                \
      const int ba_ = j0a_ * PITCH + 8 * g_;                                   \
      const int bb_ = ba_ + 16 * PITCH;                                        \
      f4 c1a = {0.f,0.f,0.f,0.f}, c2a = {0.f,0.f,0.f,0.f};                     \
      f4 c1b = {0.f,0.f,0.f,0.f}, c2b = {0.f,0.f,0.f,0.f};                     \
      MSTEP(0); MSTEP(1); MSTEP(2); MSTEP(3); MSTEP(4); MSTEP(5); MSTEP(6);    \
      MSTEP(7); MSTEP(8); MSTEP(9); MSTEP(10); MSTEP(11); MSTEP(12);           \
      const int ygg_ = yg + 8 * g_;                                            \
      _Pragma("unroll")                                                        \
      for (int half = 0; half < 2; ++half) {                                   \
        const int gx_ = j0a_ + half * 16 + row;                                \
        const f4 t1 = half ? c1b : c1a;                                        \
        const f4 t2 = half ? c2b : c2a;                                        \
        _Pragma("unroll")                                                      \
        for (int reg = 0; reg < 4; ++reg) {                                    \
          const int r_ = kg * 4 + reg;                                         \
          out[(((size_t)n * 192 + ch * 3 + (r_ & 1)) * 256 + (ygg_ + (r_ >> 1))) * 256 + gx_] = t1[reg]; \
        }                                                                      \
        if (kg < 2) {                                                          \
          _Pragma("unroll")                                                    \
          for (int reg = 0; reg < 4; ++reg) {                                  \
            const int r_ = kg * 4 + reg;                                       \
            out[(((size_t)n * 192 + ch * 3 + 2) * 256 + (ygg_ + r_)) * 256 + gx_] = t2[reg]; \
          }                                                                    \
        }                                                                      \
      }                                                                        \
    }                                                                          \
  } while (0)

  #pragma unroll 1
  for (int j = 0; j < 8; ++j) {
    const int yg = j << 5;
    const bool pf = (j < 7);
    const int ygn = yg + 32;
    const _Float16* curp = Xt[j & 1];
    _Float16* nxtp = Xt[(j + 1) & 1];

    PAIR_BLOCK(0); PAIR_BLOCK(1); PAIR_BLOCK(2); PAIR_BLOCK(3);
    PAIR_BLOCK(4); PAIR_BLOCK(5); PAIR_BLOCK(6); PAIR_BLOCK(7);

    if (pf) WRITE_BATCH(6);   // last batch (loaded at pair 6)

    // item barrier: LDS ordering only -- no vmcnt(0) store drain.
    asm volatile("s_waitcnt lgkmcnt(0)" ::: "memory");
    __builtin_amdgcn_sched_barrier(0);
    __builtin_amdgcn_s_barrier();
    __builtin_amdgcn_sched_barrier(0);
  }

#undef PAIR_BLOCK
#undef MSTEP
#undef WRITE_BATCH
#undef LOAD_BATCH
#undef PITCH
}

// ---------------- launch ----------------
extern "C" void kernel_launch(void* const* d_in, const int* in_sizes, int n_in,
                              void* d_out, int out_size, void* d_ws, size_t ws_size,
                              hipStream_t stream) {
  const float* xin = (const float*)d_in[0];
  const float* A1 = (const float*)d_in[1];
  const float* B1 = (const float*)d_in[2];
  const float* A2 = (const float*)d_in[3];
  const float* B2 = (const float*)d_in[4];
  const float* A3 = (const float*)d_in[5];
  const float* B3 = (const float*)d_in[6];
  const float* dw_w3 = (const float*)d_in[7];
  const float* dw_b3 = (const float*)d_in[8];
  const float* w1_3 = (const float*)d_in[9];
  const float* b1_3 = (const float*)d_in[10];
  const float* w2_3 = (const float*)d_in[11];
  const float* b2_3 = (const float*)d_in[12];
  const float* dilw3 = (const float*)d_in[13];
  const float* dw_w5 = (const float*)d_in[14];
  const float* dw_b5 = (const float*)d_in[15];
  const float* w1_5 = (const float*)d_in[16];
  const float* b1_5 = (const float*)d_in[17];
  const float* w2_5 = (const float*)d_in[18];
  const float* b2_5 = (const float*)d_in[19];
  const float* dilw5 = (const float*)d_in[20];
  const float* dw_w9 = (const float*)d_in[21];
  const float* dw_b9 = (const float*)d_in[22];
  const float* w1_9 = (const float*)d_in[23];
  const float* b1_9 = (const float*)d_in[24];
  const float* w2_9 = (const float*)d_in[25];
  const float* b2_9 = (const float*)d_in[26];
  const float* dilw9 = (const float*)d_in[27];

  _Float16* wA = (_Float16*)d_ws;  // 64 ch * 2 * 16 * 416 f16 = 1,703,936 B

  prep_kernel<<<64, 256, 0, stream>>>(
      A1, B1, A2, B2, A3, B3,
      dw_w3, dw_b3, w1_3, b1_3, w2_3, b2_3, dilw3,
      dw_w5, dw_b5, w1_5, b1_5, w2_5, b2_5, dilw5,
      dw_w9, dw_b9, w1_9, b1_9, w2_9, b2_9, dilw9,
      wA);

  conv_mfma_kernel<<<dim3(512), 256, 0, stream>>>(xin, wA, (float*)d_out);
}

// Round 15
// 176.479 us; speedup vs baseline: 1.0277x; 1.0277x over previous
//
#include <hip/hip_runtime.h>
#include <cstddef>

typedef _Float16 h8 __attribute__((ext_vector_type(8)));
typedef float f4 __attribute__((ext_vector_type(4)));
typedef unsigned int uint32;

// ---------------- prep kernel: synthesize merged 17x17 kernels ----------------
struct BranchP {
  int ksz, scale, CIN, HID, COUT, S, nd;
  int dils[3];
  const float *dw_w, *dw_b, *w1, *b1, *w2, *b2, *dilw;
};

__device__ void run_branch(int tid, const BranchP P,
                           const float* w0, float* merged,
                           float* bufA, float* bufB) {
  const int S = P.S, ksz = P.ksz, CIN = P.CIN, HID = P.HID, COUT = P.COUT;
  const int SS = S * S;
  // 1) pad (bottom/right) + pixel_unshuffle (scale==1 -> copy)
  for (int i = tid; i < CIN * SS; i += 256) {
    const int cc = i / SS, rem = i % SS, hh = rem / S, ww = rem % S;
    const int s2 = P.scale * P.scale;
    const int c = cc / s2, r2 = cc % s2, si = r2 / P.scale, sj = r2 % P.scale;
    const int sh = hh * P.scale + si, sw = ww * P.scale + sj;
    bufA[i] = (sh < 17 && sw < 17) ? w0[c * 289 + sh * 17 + sw] : 0.f;
  }
  __syncthreads();
  // 2) depthwise 3x3, pad 1
  for (int i = tid; i < CIN * SS; i += 256) {
    const int ch = i / SS, rem = i % SS, y = rem / S, x = rem % S;
    float acc = P.dw_b[ch];
    for (int u = 0; u < 3; ++u)
      for (int v = 0; v < 3; ++v) {
        const int yy = y + u - 1, xx = x + v - 1;
        if (yy >= 0 && yy < S && xx >= 0 && xx < S)
          acc += bufA[ch * SS + yy * S + xx] * P.dw_w[ch * 9 + u * 3 + v];
      }
    bufB[i] = acc;
  }
  __syncthreads();
  // 3) 1x1 + bias + relu  (bufB -> bufA)
  for (int i = tid; i < HID * SS; i += 256) {
    const int ho = i / SS, rem = i % SS;
    float acc = P.b1[ho];
    for (int ci = 0; ci < CIN; ++ci) acc += bufB[ci * SS + rem] * P.w1[ho * CIN + ci];
    bufA[i] = fmaxf(acc, 0.f);
  }
  __syncthreads();
  // 4) 1x1 + bias  (bufA -> bufB)
  for (int i = tid; i < COUT * SS; i += 256) {
    const int po = i / SS, rem = i % SS;
    float acc = P.b2[po];
    for (int ci = 0; ci < HID; ++ci) acc += bufA[ci * SS + rem] * P.w2[po * HID + ci];
    bufB[i] = acc;
  }
  __syncthreads();
  // 5) bilinear S -> ksz  (bufB -> bufA)
  for (int i = tid; i < COUT * ksz * ksz; i += 256) {
    const int c = i / (ksz * ksz), rem = i % (ksz * ksz), oy = rem / ksz, ox = rem % ksz;
    const float ratio = (float)S / (float)ksz;
    float sy = fminf(fmaxf((oy + 0.5f) * ratio - 0.5f, 0.f), (float)(S - 1));
    float sx = fminf(fmaxf((ox + 0.5f) * ratio - 0.5f, 0.f), (float)(S - 1));
    const int y0 = (int)sy; const int y1 = min(y0 + 1, S - 1); const float ty = sy - (float)y0;
    const int x0 = (int)sx; const int x1 = min(x0 + 1, S - 1); const float tx = sx - (float)x0;
    const float* img = bufB + c * SS;
    const float top = img[y0 * S + x0] * (1.f - tx) + img[y0 * S + x1] * tx;
    const float bot = img[y1 * S + x0] * (1.f - tx) + img[y1 * S + x1] * tx;
    bufA[i] = top * (1.f - ty) + bot * ty;
  }
  __syncthreads();
  // 6) per-dil channel mix + zero-interleave + accumulate into merged
  for (int di = 0; di < P.nd; ++di) {
    const int d = P.dils[di];
    const int e = d * (ksz - 1) + 1, pp = 8 - e / 2;
    for (int i = tid; i < 3 * ksz * ksz; i += 256) {
      const int p = i / (ksz * ksz), rem = i % (ksz * ksz), ih = rem / ksz, iw = rem % ksz;
      float acc = 0.f;
      for (int c2 = 0; c2 < COUT; ++c2)
        acc += bufA[c2 * ksz * ksz + rem] * P.dilw[(di * 3 + p) * COUT + c2];
      merged[p * 289 + (pp + d * ih) * 17 + (pp + d * iw)] += acc;
    }
  }
  __syncthreads();
}

// A-matrix geometry: K = 17 dx-cols x 24 rows = 408, padded to 416 (13 x K32).
//   k = dxi*24 + r ; dxi = dx+8 in [0,16] ; r = local X row (rel. to ygroup base).
//   G1 (M=16): m = y_off*2 + pp, pp in {0,1};  G2: m = y_off (p=2), m>=8 zero.
//   A[m][k] = merged[pp][dy+8][dxi], dy = r - 8 - y_off (zero outside [-8,8]).
#define KPAD 416
#define ACH (2 * 16 * KPAD)   // f16 elements per channel (both GEMMs)

__global__ __launch_bounds__(256) void prep_kernel(
    const float* __restrict__ A1, const float* __restrict__ B1,
    const float* __restrict__ A2, const float* __restrict__ B2,
    const float* __restrict__ A3, const float* __restrict__ B3,
    const float* __restrict__ dw_w3, const float* __restrict__ dw_b3,
    const float* __restrict__ w1_3, const float* __restrict__ b1_3,
    const float* __restrict__ w2_3, const float* __restrict__ b2_3,
    const float* __restrict__ dilw3,
    const float* __restrict__ dw_w5, const float* __restrict__ dw_b5,
    const float* __restrict__ w1_5, const float* __restrict__ b1_5,
    const float* __restrict__ w2_5, const float* __restrict__ b2_5,
    const float* __restrict__ dilw5,
    const float* __restrict__ dw_w9, const float* __restrict__ dw_b9,
    const float* __restrict__ w1_9, const float* __restrict__ b1_9,
    const float* __restrict__ w2_9, const float* __restrict__ b2_9,
    const float* __restrict__ dilw9,
    _Float16* __restrict__ wA) {
  const int o = blockIdx.x;
  const int tid = threadIdx.x;
  __shared__ float w0[3 * 289];
  __shared__ float merged[3 * 289];
  __shared__ float bufA[3888];
  __shared__ float bufB[3888];

  // weight0[o,c] = A_c[o] (17x4) @ B_c[o] (4x17)
  for (int i = tid; i < 3 * 289; i += 256) {
    const int c = i / 289, rem = i % 289, k = rem / 17, l = rem % 17;
    const float* A = (c == 0 ? A1 : (c == 1 ? A2 : A3)) + o * 68;
    const float* B = (c == 0 ? B1 : (c == 1 ? B2 : B3)) + o * 68;
    float s = 0.f;
    for (int r = 0; r < 4; ++r) s += A[k * 4 + r] * B[r * 17 + l];
    w0[i] = s;
    merged[i] = 0.f;
  }
  __syncthreads();

  {
    BranchP P{3, 4, 48, 64, 12, 5, 3, {4, 5, 7}, dw_w3, dw_b3, w1_3, b1_3, w2_3, b2_3, dilw3};
    run_branch(tid, P, w0, merged, bufA, bufB);
  }
  {
    BranchP P{5, 2, 12, 48, 6, 9, 1, {1, 0, 0}, dw_w5, dw_b5, w1_5, b1_5, w2_5, b2_5, dilw5};
    run_branch(tid, P, w0, merged, bufA, bufB);
  }
  {
    BranchP P{9, 1, 3, 12, 3, 17, 1, {2, 0, 0}, dw_w9, dw_b9, w1_9, b1_9, w2_9, b2_9, dilw9};
    run_branch(tid, P, w0, merged, bufA, bufB);
  }

  // pack A-matrices (f16, RTE) for both GEMMs
  for (int i = tid; i < ACH; i += 256) {
    const int g = i / (16 * KPAD);
    const int m = (i / KPAD) % 16;
    const int k = i % KPAD;
    const int dxi = k / 24, r = k % 24;
    int pp, yo;
    if (g == 0) { pp = m & 1; yo = m >> 1; } else { pp = 2; yo = m; }
    const int dy = r - 8 - yo;
    float val = 0.f;
    if (!(g == 1 && m >= 8) && dy >= -8 && dy <= 8 && dxi <= 16)
      val = merged[pp * 289 + (dy + 8) * 17 + dxi];
    wA[(size_t)o * ACH + i] = (_Float16)val;
  }
}

// ---------------- main conv kernel (MFMA, persistent y-strip, dbuf) ----------------
// 512 blocks (2/CU resident, 2 waves/SIMD), each owns one (n,ch) strip =
// 8 items x 32 output rows x 256 cols. LDS double-buffer: compute item j from
// buf[j&1] while item j+1's stage (7 batches: 8 coalesced dword loads -> regs
// -> cvt -> b128 write to buf[(j+1)&1]) is interleaved at pair boundaries.
// One __syncthreads per item: orders nxt-writes before j+1 reads; cur-reads
// finish before j+1 overwrites cur (first write to old-cur is after barrier).
// A fragments (a1,a2: 104 VGPR) loaded ONCE per block, reused 8 items x 16.
// Per item: 8 col-tile PAIRS (R8 structure): 26 ds_read_b128 + 52 MFMA each.
// LDS 2x31.4 KB = 62.7 KB -> exactly 2 blocks/CU.
__global__ __launch_bounds__(256, 2) void conv_mfma_kernel(
    const float* __restrict__ xin, const _Float16* __restrict__ wA,
    float* __restrict__ out) {
  // XCD swizzle: 512 = 8 XCDs x 64; consecutive (n,ch) strips share nothing,
  // but blocks within an XCD stay contiguous in ch for wA L2 locality.
  const int blk = ((blockIdx.x & 7) << 6) + (blockIdx.x >> 3);
  const int n  = blk >> 6;
  const int ch = blk & 63;
  const int tid = threadIdx.x;

#define PITCH 56
  __shared__ __align__(16) _Float16 Xt[2][280 * PITCH];  // 2 x 31,360 B

  const float* xim = xin + ((size_t)(n * 64 + ch)) * 65536;

  const int lane = tid & 63;
  const int wv = tid >> 6;
  const int row = lane & 15;   // A-row / B-col / C-col lane index
  const int kg = lane >> 4;    // k-slice group (8 k's each)

  // ---- A fragments: loaded once per block, reused for all 8 items ----
  h8 a1[13], a2[13];
  {
    const _Float16* Ab = wA + (size_t)ch * ACH + row * KPAD;
    #pragma unroll
    for (int t = 0; t < 13; ++t) {
      const int k0 = t * 32 + kg * 8;
      a1[t] = __builtin_bit_cast(h8, *(const uint4*)(Ab + k0));
      a2[t] = __builtin_bit_cast(h8, *(const uint4*)(Ab + 16 * KPAD + k0));
    }
  }

  // ---- B-fragment LDS offsets (item-independent) ----
  int boff[13];
  #pragma unroll
  for (int t = 0; t < 13; ++t) {
    const int k0 = t * 32 + kg * 8;
    const int dxi = k0 / 24, r0 = k0 - dxi * 24;   // 8 consecutive k in one dxi
    boff[t] = (row + dxi) * PITCH + r0;
  }

  // ---- prologue: stage item 0 (rows -8..39) into Xt[0] ----
  for (int i = tid; i < 6 * 280; i += 256) {
    const int rb = i / 280, c = i % 280;
    const int gx = c - 8;
    const bool cok = (gx >= 0 && gx < 256);
    float v[8];
    #pragma unroll
    for (int rr = 0; rr < 8; ++rr) {
      const int gy = -8 + rb * 8 + rr;
      v[rr] = (cok && gy >= 0 && gy < 256) ? xim[gy * 256 + gx] : 0.f;
    }
    uint4 u;
    u.x = __builtin_bit_cast(uint32, __builtin_amdgcn_cvt_pkrtz(v[0], v[1]));
    u.y = __builtin_bit_cast(uint32, __builtin_amdgcn_cvt_pkrtz(v[2], v[3]));
    u.z = __builtin_bit_cast(uint32, __builtin_amdgcn_cvt_pkrtz(v[4], v[5]));
    u.w = __builtin_bit_cast(uint32, __builtin_amdgcn_cvt_pkrtz(v[6], v[7]));
    *(uint4*)&Xt[0][c * PITCH + rb * 8] = u;
  }
  __syncthreads();

  float pv[8];   // one stage batch in flight (loaded pair p, written pair p+1)

#define MSTEP(t) do {                                                          \
    const h8 vba = __builtin_bit_cast(h8, *(const uint4*)&curp[ba_ + boff[t]]);\
    const h8 vbb = __builtin_bit_cast(h8, *(const uint4*)&curp[bb_ + boff[t]]);\
    c1a = __builtin_amdgcn_mfma_f32_16x16x32_f16(a1[t], vba, c1a, 0, 0, 0);    \
    c1b = __builtin_amdgcn_mfma_f32_16x16x32_f16(a1[t], vbb, c1b, 0, 0, 0);    \
    c2a = __builtin_amdgcn_mfma_f32_16x16x32_f16(a2[t], vba, c2a, 0, 0, 0);    \
    c2b = __builtin_amdgcn_mfma_f32_16x16x32_f16(a2[t], vbb, c2b, 0, 0, 0);    \
  } while (0)

#define PAIR_BLOCK(pr) do {                                                    \
    /* write stage batch pr-1 (loaded at previous pair) to next buffer */      \
    if (pf && (pr) >= 1) {                                                     \
      const int ip = tid + 256 * ((pr) - 1);                                   \
      if (ip < 1680) {                                                         \
        const int rbp = ip / 280, ccp = ip % 280;                              \
        uint4 u;                                                               \
        u.x = __builtin_bit_cast(uint32, __builtin_amdgcn_cvt_pkrtz(pv[0], pv[1])); \
        u.y = __builtin_bit_cast(uint32, __builtin_amdgcn_cvt_pkrtz(pv[2], pv[3])); \
        u.z = __builtin_bit_cast(uint32, __builtin_amdgcn_cvt_pkrtz(pv[4], pv[5])); \
        u.w = __builtin_bit_cast(uint32, __builtin_amdgcn_cvt_pkrtz(pv[6], pv[7])); \
        *(uint4*)&nxtp[ccp * PITCH + rbp * 8] = u;                             \
      }                                                                        \
    }                                                                          \
    /* issue stage batch pr loads (latency hidden under this pair) */          \
    if (pf && (pr) <= 6) {                                                     \
      const int il = tid + 256 * (pr);                                         \
      if (il < 1680) {                                                         \
        const int rbl = il / 280, ccl = il % 280;                              \
        const int gx = ccl - 8;                                                \
        const bool cok = (gx >= 0 && gx < 256);                                \
        _Pragma("unroll")                                                      \
        for (int rr = 0; rr < 8; ++rr) {                                       \
          const int gy = ygn - 8 + rbl * 8 + rr;                               \
          pv[rr] = (cok && gy >= 0 && gy < 256) ? xim[gy * 256 + gx] : 0.f;    \
        }                                                                      \
      }                                                                        \
    }                                                                          \
    /* compute pair */                                                         \
    {                                                                          \
      const int g_ = (pr) >> 1, cp_ = (pr) & 1;                                \
      const int j0a_ = (wv * 4 + cp_ * 2) * 16;                                \
      const int ba_ = j0a_ * PITCH + 8 * g_;                                   \
      const int bb_ = ba_ + 16 * PITCH;                                        \
      f4 c1a = {0.f,0.f,0.f,0.f}, c2a = {0.f,0.f,0.f,0.f};                     \
      f4 c1b = {0.f,0.f,0.f,0.f}, c2b = {0.f,0.f,0.f,0.f};                     \
      MSTEP(0); MSTEP(1); MSTEP(2); MSTEP(3); MSTEP(4); MSTEP(5); MSTEP(6);    \
      MSTEP(7); MSTEP(8); MSTEP(9); MSTEP(10); MSTEP(11); MSTEP(12);           \
      const int ygg_ = yg + 8 * g_;                                            \
      _Pragma("unroll")                                                        \
      for (int half = 0; half < 2; ++half) {                                   \
        const int gx_ = j0a_ + half * 16 + row;                                \
        const f4 t1 = half ? c1b : c1a;                                        \
        const f4 t2 = half ? c2b : c2a;                                        \
        _Pragma("unroll")                                                      \
        for (int reg = 0; reg < 4; ++reg) {                                    \
          const int r_ = kg * 4 + reg;                                         \
          out[(((size_t)n * 192 + ch * 3 + (r_ & 1)) * 256 + (ygg_ + (r_ >> 1))) * 256 + gx_] = t1[reg]; \
        }                                                                      \
        if (kg < 2) {                                                          \
          _Pragma("unroll")                                                    \
          for (int reg = 0; reg < 4; ++reg) {                                  \
            const int r_ = kg * 4 + reg;                                       \
            out[(((size_t)n * 192 + ch * 3 + 2) * 256 + (ygg_ + r_)) * 256 + gx_] = t2[reg]; \
          }                                                                    \
        }                                                                      \
      }                                                                        \
    }                                                                          \
  } while (0)

  #pragma unroll 1
  for (int j = 0; j < 8; ++j) {
    const int yg = j << 5;
    const bool pf = (j < 7);
    const int ygn = yg + 32;
    const _Float16* curp = Xt[j & 1];
    _Float16* nxtp = Xt[(j + 1) & 1];

    PAIR_BLOCK(0); PAIR_BLOCK(1); PAIR_BLOCK(2); PAIR_BLOCK(3);
    PAIR_BLOCK(4); PAIR_BLOCK(5); PAIR_BLOCK(6); PAIR_BLOCK(7);

    __syncthreads();   // nxt visible; cur reads done before next overwrites
  }

#undef PAIR_BLOCK
#undef MSTEP
#undef PITCH
}

// ---------------- launch ----------------
extern "C" void kernel_launch(void* const* d_in, const int* in_sizes, int n_in,
                              void* d_out, int out_size, void* d_ws, size_t ws_size,
                              hipStream_t stream) {
  const float* xin = (const float*)d_in[0];
  const float* A1 = (const float*)d_in[1];
  const float* B1 = (const float*)d_in[2];
  const float* A2 = (const float*)d_in[3];
  const float* B2 = (const float*)d_in[4];
  const float* A3 = (const float*)d_in[5];
  const float* B3 = (const float*)d_in[6];
  const float* dw_w3 = (const float*)d_in[7];
  const float* dw_b3 = (const float*)d_in[8];
  const float* w1_3 = (const float*)d_in[9];
  const float* b1_3 = (const float*)d_in[10];
  const float* w2_3 = (const float*)d_in[11];
  const float* b2_3 = (const float*)d_in[12];
  const float* dilw3 = (const float*)d_in[13];
  const float* dw_w5 = (const float*)d_in[14];
  const float* dw_b5 = (const float*)d_in[15];
  const float* w1_5 = (const float*)d_in[16];
  const float* b1_5 = (const float*)d_in[17];
  const float* w2_5 = (const float*)d_in[18];
  const float* b2_5 = (const float*)d_in[19];
  const float* dilw5 = (const float*)d_in[20];
  const float* dw_w9 = (const float*)d_in[21];
  const float* dw_b9 = (const float*)d_in[22];
  const float* w1_9 = (const float*)d_in[23];
  const float* b1_9 = (const float*)d_in[24];
  const float* w2_9 = (const float*)d_in[25];
  const float* b2_9 = (const float*)d_in[26];
  const float* dilw9 = (const float*)d_in[27];

  _Float16* wA = (_Float16*)d_ws;  // 64 ch * 2 * 16 * 416 f16 = 1,703,936 B

  prep_kernel<<<64, 256, 0, stream>>>(
      A1, B1, A2, B2, A3, B3,
      dw_w3, dw_b3, w1_3, b1_3, w2_3, b2_3, dilw3,
      dw_w5, dw_b5, w1_5, b1_5, w2_5, b2_5, dilw5,
      dw_w9, dw_b9, w1_9, b1_9, w2_9, b2_9, dilw9,
      wA);

  conv_mfma_kernel<<<dim3(512), 256, 0, stream>>>(xin, wA, (float*)d_out);
}